// Round 9
// baseline (89.344 us; speedup 1.0000x reference)
//
#include <hip/hip_runtime.h>

#define VOCAB 4096
#define SLICES 16
#define SLICE 256            // codes per slice (16-way split per point-set)
#define TRK 32               // codes per TRACKED super-group (margin unit)
#define NSUP (SLICE / TRK)   // 8 super-groups per slice
#define P 2                  // points per lane
#define PTS (64 * P)         // 128 points per block
#define THREADS 1024

typedef float f2 __attribute__((ext_vector_type(2)));

// Forced packed fp32 FMA: v_pk_fma_f32 (VOP3P; full-rate on gfx950 per
// R3/R6 busy-time audit). Per-element bit-identical to v_fma_f32.
// NOTE (R7): v_pk_max_f32 does NOT exist on gfx950 — max tree uses scalar
// v_max3_f32 folding. sv-form: e from wave-uniform s_load (one 64-bit
// scalar operand allowed). vv-form: e from LDS (VGPR) — no scalar slot
// needed, so h rides in VGPR with no mov.
__device__ __forceinline__ f2 pkfma_sv(f2 x, f2 e, f2 c) {
  f2 d;
  asm("v_pk_fma_f32 %0, %1, %2, %3" : "=v"(d) : "v"(x), "s"(e), "v"(c));
  return d;
}
__device__ __forceinline__ f2 pkfma_vv(f2 x, f2 e, f2 c) {
  f2 d;
  asm("v_pk_fma_f32 %0, %1, %2, %3" : "=v"(d) : "v"(x), "v"(e), "v"(c));
  return d;
}

// Empty-asm register barrier: forces the value into a VGPR, preventing
// fma-contraction / reassociation across it. Emits no instruction.
__device__ __forceinline__ float opaque(float x) {
  asm volatile("" : "+v"(x));
  return x;
}

// v_max3_f32: exact 3-input max (identical result to nested fmaxf).
__device__ __forceinline__ float max3f(float a, float b, float c) {
  float d;
  asm("v_max3_f32 %0, %1, %2, %3" : "=v"(d) : "v"(a), "v"(b), "v"(c));
  return d;
}

// v_med3_f32: with invariant t2 <= t1, med3(t1, t2, gm) == max(t2, min(t1,gm))
// (exact selection). 1 slot instead of 2.
__device__ __forceinline__ float med3f(float a, float b, float c) {
  float d;
  asm("v_med3_f32 %0, %1, %2, %3" : "=v"(d) : "v"(a), "v"(b), "v"(c));
  return d;
}

// Code pair, SoA-interleaved: {e0a,e0b}, {e1a,e1b}, {e2a,e2b}, {ha,hb}.
struct alignas(16) CPair { f2 e0, e1, e2, h; };   // 32 B

// Prep: pack per-code {e0, e1, e2, h} where h = -0.5f*c and
// c = ((e0*e0+e1*e1)+e2*e2) rounded exactly like numpy (each product/sum
// individually rounded f32). h is an exact scale of c (exponent shift),
// so c = -2*h is recoverable bit-exactly. (Validated R10/R12/R13.)
// Also writes the pair-interleaved copy used by phase 1.
__global__ __launch_bounds__(256) void vq_prep_kernel(
    const float* __restrict__ cb, float4* __restrict__ cw,
    float* __restrict__ cwp, float* __restrict__ loss_slot) {
  int j = blockIdx.x * 256 + threadIdx.x;
  if (j == 0) *loss_slot = 0.0f;
  if (j < VOCAB) {
    float e0 = cb[3 * j + 0];
    float e1 = cb[3 * j + 1];
    float e2 = cb[3 * j + 2];
    float p0 = opaque(e0 * e0);
    float p1 = opaque(e1 * e1);
    float p2 = opaque(e2 * e2);
    float c = opaque(opaque(p0 + p1) + p2);
    float h = -0.5f * c;
    cw[j] = make_float4(e0, e1, e2, h);
    int i = j >> 1, o = j & 1;          // pair id, slot within pair
    cwp[i * 8 + 0 + o] = e0;
    cwp[i * 8 + 2 + o] = e1;
    cwp[i * 8 + 4 + o] = e2;
    cwp[i * 8 + 6 + o] = h;
  }
}

// Bit-exact numpy f32 distance (validated absmax=0.0 R10/R12/R13):
//   m = x.e (fma ascending k, first term single-rounded mul)
//   d = (a - 2m) + c;  c = -2*h exact (fma-contract-safe).
__device__ __forceinline__ float dist_f32(float x0, float x1, float x2,
                                          float a, float4 cd) {
  float m = fmaf(x2, cd.z, fmaf(x1, cd.y, x0 * cd.x));
  return fmaf(-2.0f, m, a) + (-2.0f * cd.w);
}

// Main: 512 blocks x 1024 threads; block = 128 points (2/lane) x 16 slices.
// R8 proved phase-1 ALU has slack (halving slots = no wall change) — the
// wall is CODE DELIVERY. R0 (pure LDS) and R1 (pure SMEM) hit identical
// 40.2us walls: each pipe alone costs ~20us/CU. This round SPLITS delivery:
// even chunks via s_load (SGPR pkfma_sv), odd chunks staged once in LDS
// (32 KB) and read via broadcast ds_read_b128 (all-VGPR pkfma_vv, h free).
// Both pipes run concurrently across drifting waves -> per-pipe ~10us,
// overlapped with ~8us VALU. Same values, same op order -> bit-identical.
__global__ __launch_bounds__(THREADS, 8) void vq_kernel(
    const float* __restrict__ feats, const float4* __restrict__ cw,
    const CPair* __restrict__ cp, float* __restrict__ out_quant,
    float* __restrict__ out_idx, float* __restrict__ out_loss, int npts) {
  __shared__ CPair sOdd[SLICES * 64];       // 32 KB: odd chunks, all slices
  __shared__ float sT1[SLICES * PTS];       // 8 KB per-slice best t
  __shared__ float sT2[SLICES * PTS];       // 8 KB per-slice 2nd-best
  __shared__ int sG[SLICES * PTS];          // 8 KB per-slice group base
  __shared__ unsigned long long sSlot[PTS]; // 1 KB fallback (d,idx) keys
  __shared__ float4 sFP[PTS];               // 2 KB flagged-point coords
  __shared__ int sList[PTS];                // 0.5 KB flagged point ids
  __shared__ int sCount;
  __shared__ double sPart[2];               // per-wave loss partials

  const int tid = threadIdx.x;
  const int lane = tid & 63;
  // Wave-uniform slice id (readfirstlane: proven uniform -> scalar path).
  const int s = __builtin_amdgcn_readfirstlane(tid >> 6);

  if (tid == 0) sCount = 0;

  // Stage ODD chunks of every slice into LDS (compact layout): slice ss
  // contributes its 16 odd chunks (x4 CPairs). Thread t stages one CPair:
  // ss = t>>6, q = t&63, odd-chunk oc = q>>2 (0..15), pair-in-chunk q&3.
  {
    const int ss = tid >> 6, q = tid & 63;
    const int oc = q >> 2, pic = q & 3;
    sOdd[tid] = cp[ss * 128 + (2 * oc + 1) * 4 + pic];
  }

  const int pbase = blockIdx.x * PTS;
  // Lane's P points: pbase + k*64 + lane, k = 0..P-1 (same for all waves).
  float px[P], py[P], pz[P], nn[P];
#pragma unroll
  for (int k = 0; k < P; ++k) {
    const int p = pbase + k * 64 + lane;
    px[k] = feats[3 * p + 0];
    py[k] = feats[3 * p + 1];
    pz[k] = feats[3 * p + 2];
    // ||x||^2 exactly as numpy: products rounded, then ((p0+p1)+p2)
    float q0 = opaque(px[k] * px[k]);
    float q1 = opaque(py[k] * py[k]);
    float q2 = opaque(pz[k] * pz[k]);
    nn[k] = opaque(opaque(q0 + q1) + q2);
  }

  __syncthreads();  // sOdd staged

  // Phase 1: surrogate max-scan over this wave's 256-code slice.
  f2 X[P], Y[P], Z[P];
#pragma unroll
  for (int k = 0; k < P; ++k) {
    X[k] = (f2){px[k], px[k]};
    Y[k] = (f2){py[k], py[k]};
    Z[k] = (f2){pz[k], pz[k]};
  }
  const CPair* cs = cp + s * (SLICE / 2);   // 128 pairs per slice (global)
  const CPair* ls = sOdd + s * 64;          // 64 staged pairs (LDS)
  float t1[P], t2[P];
  int gg[P];
#pragma unroll
  for (int k = 0; k < P; ++k) { t1[k] = -3.4e38f; t2[k] = -3.4e38f; gg[k] = 0; }
#pragma unroll 2
  for (int g = 0; g < NSUP; ++g) {
    const CPair* gp = cs + g * 16;          // global pairs, supergroup g
    const CPair* lp = ls + g * 8;           // staged odd pairs, supergroup g
    float mm[P];
#pragma unroll
    for (int k = 0; k < P; ++k) mm[k] = -3.4e38f;
#pragma unroll
    for (int c = 0; c < 4; ++c) {           // chunks: even=SMEM, odd=LDS
      if ((c & 1) == 0) {
        const CPair* ck = gp + (c >> 1) * 8;  // chunk0 -> gp[0..3], chunk2 -> gp[8..11]
#pragma unroll
        for (int j = 0; j < 4; ++j) {
          CPair a = ck[j];
          f2 H = a.h;                         // one VGPR copy, shared by P pts
          asm volatile("" : "+v"(H));
#pragma unroll
          for (int k = 0; k < P; ++k) {
            f2 u = pkfma_sv(X[k], a.e0, pkfma_sv(Y[k], a.e1, pkfma_sv(Z[k], a.e2, H)));
            mm[k] = max3f(u.x, u.y, mm[k]);   // exact associative fold
          }
        }
      } else {
        const CPair* ck = lp + (c >> 1) * 4;  // chunk1 -> lp[0..3], chunk3 -> lp[4..7]
#pragma unroll
        for (int j = 0; j < 4; ++j) {
          CPair b = ck[j];                    // ds_read_b128 x2, broadcast
#pragma unroll
          for (int k = 0; k < P; ++k) {
            f2 u = pkfma_vv(X[k], b.e0, pkfma_vv(Y[k], b.e1, pkfma_vv(Z[k], b.e2, b.h)));
            mm[k] = max3f(u.x, u.y, mm[k]);
          }
        }
      }
    }
#pragma unroll
    for (int k = 0; k < P; ++k) {
      float gm = mm[k];                      // super-group max (exact)
      t2[k] = med3f(t1[k], t2[k], gm);       // streaming top-2 (med3 trick)
      if (gm > t1[k]) gg[k] = g;             // strict >: earliest group
      t1[k] = fmaxf(t1[k], gm);
    }
  }
#pragma unroll
  for (int k = 0; k < P; ++k) {
    sT1[s * PTS + k * 64 + lane] = t1[k];
    sT2[s * PTS + k * 64 + lane] = t2[k];
    sG[s * PTS + k * 64 + lane] = s * SLICE + gg[k] * TRK;
  }
  __syncthreads();

  // Epilogue combine: tid < 128 owns block-point pt == tid; its coords are
  // its own registers' point k == s (waves 0..1 cover tid 0..127).
  int bi = 0;
  float q0 = 0.0f, q1 = 0.0f, q2 = 0.0f;
  bool flagged = false;
  float x0 = px[0], x1 = py[0], x2 = pz[0], a = nn[0];
#pragma unroll
  for (int k = 1; k < P; ++k) {
    if (s == k) { x0 = px[k]; x1 = py[k]; x2 = pz[k]; a = nn[k]; }
  }
  if (tid < PTS) {
    float b1 = sT1[tid], b2 = sT2[tid];
    int gbase = sG[tid];
#pragma unroll
    for (int k = 1; k < SLICES; ++k) {  // ascending slice order
      float u1 = sT1[k * PTS + tid];
      float u2 = sT2[k * PTS + tid];
      b2 = fmaxf(fmaxf(b2, u2), fminf(b1, u1));
      if (u1 > b1) gbase = sG[k * PTS + tid];
      b1 = fmaxf(b1, u1);
    }
    // Margin test (validated R10/R12/R13): eps = a*2^-21 + 2^-20 (2x safe);
    // group size does not enter the bound (per-code skew).
    float eps = fmaf(a, 0x1p-21f, 0x1p-20f);
    flagged = !((b1 - b2) > eps);
    if (flagged) {
      int pos = atomicAdd(&sCount, 1);
      sList[pos] = tid;
      sSlot[tid] = ~0ULL;
      sFP[tid] = make_float4(x0, x1, x2, a);  // phase-2 reads LDS, not HBM
    } else {
      // Bit-exact rescan of the certified 32-code group (global, L1/L2-hot);
      // ascending, strict <: np.argmin first-occurrence.
      float bd = 3.4e38f;
#pragma unroll 8
      for (int k = 0; k < TRK; ++k) {
        float4 cd = cw[gbase + k];
        float d = dist_f32(x0, x1, x2, a, cd);
        if (d < bd) { bd = d; bi = gbase + k; q0 = cd.x; q1 = cd.y; q2 = cd.z; }
      }
    }
  }
  __syncthreads();

  // Phase 2: cooperative bit-exact full rescan for flagged points.
  // 1024 threads x 4 codes each; sortable (d,idx) key min-reduce: min key
  // == min d, tie -> min idx (first occurrence).
  const int cnt = sCount;
  for (int f = 0; f < cnt; ++f) {
    const int fpt = sList[f];
    float4 fp = sFP[fpt];           // same addr all threads -> LDS broadcast
    float y0 = fp.x, y1 = fp.y, y2 = fp.z;
    float ay = fp.w;                // same opaque-rounded value as at load
    float bd = 3.4e38f;
    int bj = 0;
#pragma unroll
    for (int k = 0; k < VOCAB / THREADS; ++k) {
      int j = tid + k * THREADS;
      float4 cd = cw[j];
      float d = dist_f32(y0, y1, y2, ay, cd);
      if (d < bd) { bd = d; bj = j; }
    }
    unsigned b = __float_as_uint(bd);
    b = (b & 0x80000000u) ? ~b : (b | 0x80000000u);  // total-order transform
    unsigned long long key = ((unsigned long long)b << 32) | (unsigned)bj;
#pragma unroll
    for (int off = 1; off < 64; off <<= 1) {         // wave min-butterfly
      unsigned long long o = __shfl_xor(key, off);
      key = (o < key) ? o : key;
    }
    if (lane == 0) atomicMin(&sSlot[fpt], key);      // 16 atomics/point
  }
  __syncthreads();

  double lsum = 0.0;
  if (tid < PTS) {
    if (flagged) {
      bi = (int)(unsigned)(sSlot[tid] & 0xFFFFFFFFu);
      float4 cd = cw[bi];
      q0 = cd.x; q1 = cd.y; q2 = cd.z;
    }
    const int p = pbase + tid;
    // straight-through: t = q - x (f32), out = x + t (f32), like reference
    float t0 = q0 - x0, t1d = q1 - x1, t2d = q2 - x2;
    out_quant[3 * p + 0] = x0 + t0;
    out_quant[3 * p + 1] = x1 + t1d;
    out_quant[3 * p + 2] = x2 + t2d;
    out_idx[p] = (float)bi;
    lsum = (double)t0 * t0 + (double)t1d * t1d + (double)t2d * t2d;
  }
  // Loss: wave shuffle-tree reduce (double), waves 0..1 hold the data.
#pragma unroll
  for (int off = 32; off >= 1; off >>= 1) lsum += __shfl_down(lsum, off);
  if (lane == 0 && s < P) sPart[s] = lsum;
  __syncthreads();

  if (tid == 0) {
    double acc = sPart[0] + sPart[1];
    // loss = mean((q-x)^2) + 0.25*mean((x-q)^2) = 1.25 * sum / (npts*3)
    atomicAdd(out_loss, (float)(acc * (1.25 / ((double)npts * 3.0))));
  }
}

extern "C" void kernel_launch(void* const* d_in, const int* in_sizes, int n_in,
                              void* d_out, int out_size, void* d_ws,
                              size_t ws_size, hipStream_t stream) {
  const float* feats = (const float*)d_in[0];      // (B*L, 3) f32
  const float* cb = (const float*)d_in[1];         // (4096, 3) f32
  const int npts = in_sizes[0] / 3;                // 65536

  float* out = (float*)d_out;
  float* out_quant = out;                          // npts*3 elems
  float* out_idx = out + in_sizes[0];              // npts elems
  float* out_loss = out + in_sizes[0] + npts;      // 1 elem

  float4* cw = (float4*)d_ws;                      // 4096 * 16 B = 64 KB
  float* cwp = (float*)(cw + VOCAB);               // paired SoA copy, 64 KB

  vq_prep_kernel<<<VOCAB / 256, 256, 0, stream>>>(cb, cw, cwp, out_loss);
  vq_kernel<<<npts / PTS, THREADS, 0, stream>>>(feats, cw, (const CPair*)cwp,
                                                out_quant, out_idx, out_loss,
                                                npts);
}